// Round 4
// baseline (237.327 us; speedup 1.0000x reference)
//
#include <hip/hip_runtime.h>

// Problem constants
#define NB 64
#define NP 500
#define NC 128
#define NH 256
#define EPS_BN 1e-5f

// Edge-list geometry: 64 batches x 4 j-segments (125 j each), cap 2048
#define SEGS 4
#define CAPE 2048
#define JSEG 125

// ws word layout
#define EDGE_OFF 0
#define EDGE_WORDS (NB * SEGS * CAPE)        // 524288
#define CNT_OFF EDGE_WORDS                   // 256 words
#define BAR_OFF (CNT_OFF + 256)              // 1 word (padded to 64)
#define CT_OFF (BAR_OFF + 64)                // c matrix, feature-major [256][64]
#define H1_OFF (CT_OFF + NH * NB)
#define H2_OFF (H1_OFF + NH * NB)

// Output layout: tc[64] | tsys[64] | l2_points[4096000] | correlation[8192]
#define OUT_PTS_OFF 128
#define OUT_CORR_OFF 4096128

struct Params {
  const float* xyz;   // [B,3,N]
  const float* data;  // [B,C,N] l2_points
  const float* l3;    // [B,C]
  const float* temp;  // [B,1,N]
  const float* W0; const float* B0; const float* G0; const float* E0;
  const float* W1; const float* B1; const float* G1; const float* E1;
  const float* W2; const float* B2; const float* G2; const float* E2;
  const float* W3; const float* B3; const float* G3; const float* E3;
  const float* w4; const float* b4;
  float* out;
  float* ws;
};

// Monotone-counter grid barrier, 256 co-resident blocks (grid == CU count).
// R3 used SEQ_CST add + SEQ_CST polling: every poll emitted cache-wide
// buffer_inv, trashing per-XCD L2s while stragglers finished their phase
// (~27 us/barrier). Correct minimal protocol instead:
//   arrive:  RELEASE fetch_add  (one wbl2 -> my writes visible device-wide)
//   spin:    RELAXED load       (serviced at coherence point; NO cache ops)
//   depart:  ACQUIRE load       (one buffer_inv -> drop stale lines)
__device__ inline void gbar(unsigned* bar, unsigned target) {
  __syncthreads();
  if (threadIdx.x == 0) {
    __hip_atomic_fetch_add(bar, 1u, __ATOMIC_RELEASE, __HIP_MEMORY_SCOPE_AGENT);
    while (__hip_atomic_load(bar, __ATOMIC_RELAXED, __HIP_MEMORY_SCOPE_AGENT) <
           target) {
      __builtin_amdgcn_s_sleep(4);  // ~256 cycles between polls
    }
    (void)__hip_atomic_load(bar, __ATOMIC_ACQUIRE, __HIP_MEMORY_SCOPE_AGENT);
  }
  __syncthreads();
}

__global__ __launch_bounds__(256) void mega(Params p) {
  const int blk = blockIdx.x;
  const int tid = threadIdx.x;
  float* ws = p.ws;
  unsigned* bar = (unsigned*)ws + BAR_OFF;

  __shared__ union {
    struct { float4 pt[NP]; float wsum[4]; } a;        // scan + misc
    struct { float dT[16 * 504]; float corrp[16]; } c;  // corr: dT[c][j]
    struct { float part[4][64]; } l;                    // layers
  } sm;
  __shared__ int lcnt;

  // ---------------- phase A: pair scan + per-batch misc -------------------
  {
    const int b = blk >> 2;
    const int st = blk & 3;
    if (tid == 0) lcnt = 0;
    const float* xr = p.xyz + b * 1500;
    for (int idx = tid; idx < NP; idx += 256) {
      float x = xr[idx], y = xr[500 + idx], z = xr[1000 + idx];
      sm.a.pt[idx] = make_float4(x, y, z, x * x + y * y + z * z);
    }
    __syncthreads();

    const int j0 = st * JSEG, j1 = j0 + JSEG;
    const int i0 = tid, i1 = tid + 256;
    float4 p0 = sm.a.pt[i0];
    float4 p1 = (i1 < NP) ? sm.a.pt[i1] : make_float4(0.f, 0.f, 0.f, 0.f);
    int* eseg = (int*)ws + EDGE_OFF + (b * SEGS + st) * CAPE;

    for (int j = j0; j < j1; ++j) {
      float4 q = sm.a.pt[j];  // wave-uniform -> LDS broadcast
      if (i0 < j) {
        float dot = p0.x * q.x + p0.y * q.y + p0.z * q.z;
        float d = sqrtf(fabsf(p0.w + q.w - 2.f * dot));
        if (d > 0.19f && d < 0.21f) {
          int e = atomicAdd(&lcnt, 1);
          if (e < CAPE) eseg[e] = (i0 << 16) | j;
        }
      }
      if (i1 < j) {
        float dot = p1.x * q.x + p1.y * q.y + p1.z * q.z;
        float d = sqrtf(fabsf(p1.w + q.w - 2.f * dot));
        if (d > 0.19f && d < 0.21f) {
          int e = atomicAdd(&lcnt, 1);
          if (e < CAPE) eseg[e] = (i1 << 16) | j;
        }
      }
    }
    __syncthreads();
    if (tid == 0)
      ((int*)ws)[CNT_OFF + b * SEGS + st] = lcnt < CAPE ? lcnt : CAPE;

    if (blk < NB) {  // misc for batch blk
      const int b2 = blk;
      float s = 0.f;
      for (int i = tid; i < NP; i += 256) s += p.temp[b2 * NP + i];
      for (int off = 32; off; off >>= 1) s += __shfl_xor(s, off);
      if ((tid & 63) == 0) sm.a.wsum[tid >> 6] = s;
      __syncthreads();
      if (tid == 0)
        p.out[64 + b2] = (sm.a.wsum[0] + sm.a.wsum[1] + sm.a.wsum[2] +
                          sm.a.wsum[3]) * (1.f / 500.f);
      if (tid < 128) ws[CT_OFF + (128 + tid) * 64 + b2] = p.l3[b2 * NC + tid];
      if (tid == 0) p.out[b2] = p.b4[0];  // tc = bias; layer-3 atomicAdds
    }
  }
  gbar(bar, 256);

  // -------- phase B: correlation (2 chan-groups/block) + fused copy -------
  {
    const int b = blk >> 2;
    for (int pass = 0; pass < 2; ++pass) {
      const int u = 2 * blk + pass;      // unit: same b, chan-group u&7
      const int c0 = (u & 7) * 16;
      if (tid < 16) sm.c.corrp[tid] = 0.f;

      const float4* in4 = (const float4*)p.data + b * 16000 + c0 * 125;
      float4* out4 = (float4*)(p.out + OUT_PTS_OFF) + b * 16000 + c0 * 125;
      for (int idx = tid; idx < 2000; idx += 256) {
        float4 v = in4[idx];
        out4[idx] = v;                          // pass-through copy, fused
        int c = idx / 125;                      // channel 0..15
        int j4 = idx - c * 125;
        *(float4*)(&sm.c.dT[c * 504 + 4 * j4]) = v;  // contiguous b128 write
      }
      __syncthreads();

      const int quad = tid & 3;   // 4-channel group
      const int slot = tid >> 2;  // 64 edge slots
      float a0 = 0.f, a1 = 0.f, a2 = 0.f, a3 = 0.f;
      const int* cnts = (const int*)ws + CNT_OFF + b * SEGS;
      int Etot = 0;
      const float* Cb = sm.c.dT + (quad * 4) * 504;
      for (int seg = 0; seg < SEGS; ++seg) {
        int E = cnts[seg];
        Etot += E;
        const int* eseg = (const int*)ws + EDGE_OFF + (b * SEGS + seg) * CAPE;
        for (int e = slot; e < E; e += 64) {
          int ij = eseg[e];
          int i = ij >> 16, j = ij & 0xffff;
          a0 += Cb[i] * Cb[j];
          a1 += Cb[504 + i] * Cb[504 + j];
          a2 += Cb[1008 + i] * Cb[1008 + j];
          a3 += Cb[1512 + i] * Cb[1512 + j];
        }
      }
      for (int off = 4; off < 64; off <<= 1) {
        a0 += __shfl_xor(a0, off);
        a1 += __shfl_xor(a1, off);
        a2 += __shfl_xor(a2, off);
        a3 += __shfl_xor(a3, off);
      }
      if ((tid & 63) < 4) {  // one representative per quad per wave
        atomicAdd(&sm.c.corrp[quad * 4 + 0], a0);
        atomicAdd(&sm.c.corrp[quad * 4 + 1], a1);
        atomicAdd(&sm.c.corrp[quad * 4 + 2], a2);
        atomicAdd(&sm.c.corrp[quad * 4 + 3], a3);
      }
      __syncthreads();
      if (tid < 16) {
        // mask symmetric: ordered count = 2E, ordered sum = 2 * upper sum
        float denom = fmaxf(2.f * (float)Etot, 1.f);
        float v = 2.f * sm.c.corrp[tid] / denom;
        p.out[OUT_CORR_OFF + b * NC + c0 + tid] = v;
        ws[CT_OFF + (c0 + tid) * 64 + b] = v;
      }
      __syncthreads();  // protect dT/corrp before next pass restages
    }
  }
  gbar(bar, 512);

  // ---------------- phases C-F: 4 MLP layers, one feature/block -----------
  float* cT = ws + CT_OFF;
  float* hA = ws + H1_OFF;
  float* hB = ws + H2_OFF;
  const float* Wl[4] = {p.W0, p.W1, p.W2, p.W3};
  const float* Bl[4] = {p.B0, p.B1, p.B2, p.B3};
  const float* Gl[4] = {p.G0, p.G1, p.G2, p.G3};
  const float* El[4] = {p.E0, p.E1, p.E2, p.E3};
  const float* xs[4] = {cT, hA, hB, hA};
  float* ys[4] = {hA, hB, hA, nullptr};

  for (int l = 0; l < 4; ++l) {
    const int o = blk;
    const int b = tid & 63;
    const int w = tid >> 6;
    const float* wr = Wl[l] + o * NH + w * 64;
    const float* xp = xs[l] + (w * 64) * 64 + b;
    float acc = 0.f;
#pragma unroll
    for (int i = 0; i < 64; ++i) acc += xp[i * 64] * wr[i];
    sm.l.part[w][b] = acc;
    __syncthreads();
    if (w == 0) {
      float t = sm.l.part[0][b] + sm.l.part[1][b] + sm.l.part[2][b] +
                sm.l.part[3][b] + Bl[l][o];
      float s1 = t;
      for (int off = 32; off; off >>= 1) s1 += __shfl_xor(s1, off);
      float m = s1 * (1.f / 64.f);
      float d = t - m;
      float s2 = d * d;
      for (int off = 32; off; off >>= 1) s2 += __shfl_xor(s2, off);
      float var = s2 * (1.f / 64.f);
      float h = Gl[l][o] * d * rsqrtf(var + EPS_BN) + El[l][o];
      h = fmaxf(h, 0.f);
      if (l == 3) {
        atomicAdd(&p.out[b], p.w4[o] * h);
      } else {
        ys[l][o * 64 + b] = h;
      }
    }
    if (l < 3) gbar(bar, 768 + l * 256);
  }
}

extern "C" void kernel_launch(void* const* d_in, const int* in_sizes, int n_in,
                              void* d_out, int out_size, void* d_ws,
                              size_t ws_size, hipStream_t stream) {
  Params p;
  p.xyz = (const float*)d_in[0];
  p.data = (const float*)d_in[1];
  p.l3 = (const float*)d_in[2];
  p.temp = (const float*)d_in[3];
  p.W0 = (const float*)d_in[4];  p.B0 = (const float*)d_in[5];
  p.G0 = (const float*)d_in[6];  p.E0 = (const float*)d_in[7];
  p.W1 = (const float*)d_in[8];  p.B1 = (const float*)d_in[9];
  p.G1 = (const float*)d_in[10]; p.E1 = (const float*)d_in[11];
  p.W2 = (const float*)d_in[12]; p.B2 = (const float*)d_in[13];
  p.G2 = (const float*)d_in[14]; p.E2 = (const float*)d_in[15];
  p.W3 = (const float*)d_in[16]; p.B3 = (const float*)d_in[17];
  p.G3 = (const float*)d_in[18]; p.E3 = (const float*)d_in[19];
  p.w4 = (const float*)d_in[20]; p.b4 = (const float*)d_in[21];
  p.out = (float*)d_out;
  p.ws = (float*)d_ws;

  // zero the barrier counter (ws is poisoned 0xAA before every launch)
  hipMemsetAsync((char*)d_ws + BAR_OFF * sizeof(float), 0, sizeof(unsigned),
                 stream);
  mega<<<256, 256, 0, stream>>>(p);
}

// Round 5
// 232.581 us; speedup vs baseline: 1.0204x; 1.0204x over previous
//
#include <hip/hip_runtime.h>

// Problem constants
#define NB 64
#define NP 500
#define NC 128
#define NH 256
#define EPS_BN 1e-5f

// Edge-list geometry: 64 batches x 16 j-bands (32 j each), cap 512
#define SEGS 16
#define CAPE 512

// ws word layout
#define EDGE_OFF 0
#define EDGE_WORDS (NB * SEGS * CAPE)   // 524288
#define GRP_OFF EDGE_WORDS              // 64 group counters, 16-word spaced
#define ROOT_OFF (GRP_OFF + 1024)       // root counter on its own line
#define CNT_OFF (ROOT_OFF + 16)         // 64x16 edge counts
#define CT_OFF (CNT_OFF + 1024)         // c matrix, feature-major [256][64]
#define H1_OFF (CT_OFF + NH * NB)
#define H2_OFF (H1_OFF + NH * NB)

// Output layout: tc[64] | tsys[64] | l2_points[4096000] | correlation[8192]
#define OUT_PTS_OFF 128
#define OUT_CORR_OFF 4096128

struct Params {
  const float* xyz;   // [B,3,N]
  const float* data;  // [B,C,N] l2_points
  const float* l3;    // [B,C]
  const float* temp;  // [B,1,N]
  const float* W0; const float* B0; const float* G0; const float* E0;
  const float* W1; const float* B1; const float* G1; const float* E1;
  const float* W2; const float* B2; const float* G2; const float* E2;
  const float* W3; const float* B3; const float* G3; const float* E3;
  const float* w4; const float* b4;
  float* out;
  float* ws;
};

// R4 lesson: barrier fence strength was NOT the cost (seq_cst == minimal,
// ~27us/phase). The phases were latency-exposed at 1 wave/SIMD. This round:
// 1024 blocks (4 waves/SIMD) + per-batch barriers + hierarchical grid bar.

// Per-batch barrier: 16 blocks of one batch. release arrive / relaxed spin /
// acquire depart.
__device__ inline void batch_bar(unsigned* grp) {
  __syncthreads();
  if (threadIdx.x == 0) {
    __hip_atomic_fetch_add(grp, 1u, __ATOMIC_RELEASE, __HIP_MEMORY_SCOPE_AGENT);
    while (__hip_atomic_load(grp, __ATOMIC_RELAXED, __HIP_MEMORY_SCOPE_AGENT) <
           16u) {
      __builtin_amdgcn_s_sleep(1);
    }
    (void)__hip_atomic_load(grp, __ATOMIC_ACQUIRE, __HIP_MEMORY_SCOPE_AGENT);
  }
  __syncthreads();
}

// Hierarchical grid barrier: acq_rel add on group line (16 arrivals), the
// 16th promotes to root (release). Pollers watch root only (relaxed), one
// acquire on exit. Transitive happens-before: arriver rel-add -> promoter
// acq_rel RMW -> promoter rel-add root -> poller acquire.
__device__ inline void grid_bar(unsigned* grp, unsigned* root,
                                unsigned gpromote, unsigned rtarget) {
  __syncthreads();
  if (threadIdx.x == 0) {
    unsigned old = __hip_atomic_fetch_add(grp, 1u, __ATOMIC_ACQ_REL,
                                          __HIP_MEMORY_SCOPE_AGENT);
    if (old == gpromote)
      __hip_atomic_fetch_add(root, 1u, __ATOMIC_RELEASE,
                             __HIP_MEMORY_SCOPE_AGENT);
    while (__hip_atomic_load(root, __ATOMIC_RELAXED,
                             __HIP_MEMORY_SCOPE_AGENT) < rtarget) {
      __builtin_amdgcn_s_sleep(2);
    }
    (void)__hip_atomic_load(root, __ATOMIC_ACQUIRE, __HIP_MEMORY_SCOPE_AGENT);
  }
  __syncthreads();
}

#define CHK(P, I, Q, J)                                             \
  if ((I) < (J)) {                                                  \
    float dot_ = P.x * Q.x + P.y * Q.y + P.z * Q.z;                 \
    float d_ = sqrtf(fabsf(P.w + Q.w - 2.f * dot_));                \
    if (d_ > 0.19f && d_ < 0.21f) {                                 \
      int e_ = atomicAdd(&lcnt, 1);                                 \
      if (e_ < CAPE) eseg[e_] = ((I) << 16) | (J);                  \
    }                                                               \
  }

__global__ __launch_bounds__(256) void mega(Params p) {
  const int blk = blockIdx.x;
  const int tid = threadIdx.x;
  float* ws = p.ws;
  const int b = blk >> 4;   // batch (phases A/B)
  const int u = blk & 15;   // unit within batch
  unsigned* grp = (unsigned*)ws + GRP_OFF + b * 16;
  unsigned* root = (unsigned*)ws + ROOT_OFF;

  __shared__ union {
    struct { float4 pt[NP]; float wsum[4]; } a;        // scan + misc
    struct { float dT[8 * 504]; float corrp[8]; } c;   // corr: dT[c][j]
    struct { float part[4][64]; } l;                   // layers
  } sm;
  __shared__ int lcnt;

  // ---------------- phase A: pair scan (32-j band) + misc ----------------
  {
    if (tid == 0) lcnt = 0;
    const float* xr = p.xyz + b * 1500;
    for (int idx = tid; idx < NP; idx += 256) {
      float x = xr[idx], y = xr[500 + idx], z = xr[1000 + idx];
      sm.a.pt[idx] = make_float4(x, y, z, x * x + y * y + z * z);
    }
    __syncthreads();

    const int j0 = u * 32;
    const int j1 = (j0 + 32 < NP) ? j0 + 32 : NP;  // 20 for u==15
    const int i0 = tid, i1 = tid + 256;
    float4 p0 = sm.a.pt[i0];
    float4 p1 = (i1 < NP) ? sm.a.pt[i1] : make_float4(0.f, 0.f, 0.f, 0.f);
    int* eseg = (int*)ws + EDGE_OFF + (b * SEGS + u) * CAPE;

    for (int j = j0; j < j1; j += 4) {  // (j1-j0) % 4 == 0 always
      float4 q0 = sm.a.pt[j + 0];
      float4 q1 = sm.a.pt[j + 1];
      float4 q2 = sm.a.pt[j + 2];
      float4 q3 = sm.a.pt[j + 3];
      CHK(p0, i0, q0, j + 0) CHK(p0, i0, q1, j + 1)
      CHK(p0, i0, q2, j + 2) CHK(p0, i0, q3, j + 3)
      CHK(p1, i1, q0, j + 0) CHK(p1, i1, q1, j + 1)
      CHK(p1, i1, q2, j + 2) CHK(p1, i1, q3, j + 3)
    }
    __syncthreads();
    if (tid == 0)
      ((int*)ws)[CNT_OFF + b * SEGS + u] = lcnt < CAPE ? lcnt : CAPE;

    if (u == 0) {  // misc for batch b
      float s = 0.f;
      for (int i = tid; i < NP; i += 256) s += p.temp[b * NP + i];
      for (int off = 32; off; off >>= 1) s += __shfl_xor(s, off);
      if ((tid & 63) == 0) sm.a.wsum[tid >> 6] = s;
      __syncthreads();
      if (tid == 0)
        p.out[64 + b] = (sm.a.wsum[0] + sm.a.wsum[1] + sm.a.wsum[2] +
                         sm.a.wsum[3]) * (1.f / 500.f);
      if (tid < 128) ws[CT_OFF + (128 + tid) * 64 + b] = p.l3[b * NC + tid];
      if (tid == 0) p.out[b] = p.b4[0];  // tc = bias; layer-3 atomicAdds
    }
  }
  batch_bar(grp);  // round 1: grp -> 16 (per-batch, overlaps across batches)

  // -------- phase B: correlation (8 channels/block) + fused copy ---------
  {
    const int c0 = u * 8;
    if (tid < 8) sm.c.corrp[tid] = 0.f;

    const float4* in4 = (const float4*)p.data + b * 16000 + c0 * 125;
    float4* out4 = (float4*)(p.out + OUT_PTS_OFF) + b * 16000 + c0 * 125;
    for (int idx = tid; idx < 1000; idx += 256) {
      float4 v = in4[idx];
      out4[idx] = v;                               // pass-through copy, fused
      int c = idx / 125;                           // channel 0..7
      int j4 = idx - c * 125;
      *(float4*)(&sm.c.dT[c * 504 + 4 * j4]) = v;  // contiguous b128 write
    }
    __syncthreads();

    const int half = tid & 1;    // channel quad (0..3 / 4..7)
    const int slot = tid >> 1;   // 128 edge slots
    float a0 = 0.f, a1 = 0.f, a2 = 0.f, a3 = 0.f;
    const int* cb = (const int*)ws + CNT_OFF + b * SEGS;
    int cnt[SEGS];
#pragma unroll
    for (int s = 0; s < SEGS; ++s) cnt[s] = cb[s];
    int Etot = 0;
#pragma unroll
    for (int s = 0; s < SEGS; ++s) Etot += cnt[s];
    const float* Cb = sm.c.dT + half * 4 * 504;
#pragma unroll 4
    for (int s = 0; s < SEGS; ++s) {
      const int* eseg = (const int*)ws + EDGE_OFF + (b * SEGS + s) * CAPE;
      for (int e = slot; e < cnt[s]; e += 128) {
        int ij = eseg[e];
        int i = ij >> 16, j = ij & 0xffff;
        a0 += Cb[i] * Cb[j];
        a1 += Cb[504 + i] * Cb[504 + j];
        a2 += Cb[1008 + i] * Cb[1008 + j];
        a3 += Cb[1512 + i] * Cb[1512 + j];
      }
    }
    for (int off = 2; off < 64; off <<= 1) {  // preserve bit0 (half)
      a0 += __shfl_xor(a0, off);
      a1 += __shfl_xor(a1, off);
      a2 += __shfl_xor(a2, off);
      a3 += __shfl_xor(a3, off);
    }
    if ((tid & 63) < 2) {  // lanes 0 (half 0) and 1 (half 1) per wave
      atomicAdd(&sm.c.corrp[half * 4 + 0], a0);
      atomicAdd(&sm.c.corrp[half * 4 + 1], a1);
      atomicAdd(&sm.c.corrp[half * 4 + 2], a2);
      atomicAdd(&sm.c.corrp[half * 4 + 3], a3);
    }
    __syncthreads();
    if (tid < 8) {
      // mask symmetric: ordered count = 2E, ordered sum = 2 * upper sum
      float denom = fmaxf(2.f * (float)Etot, 1.f);
      float v = 2.f * sm.c.corrp[tid] / denom;
      p.out[OUT_CORR_OFF + b * NC + c0 + tid] = v;
      ws[CT_OFF + (c0 + tid) * 64 + b] = v;
    }
  }

  // ---- round 2: pre-MLP grid barrier; blocks >= 256 arrive and exit -----
  __syncthreads();
  if (blk >= 256) {
    if (tid == 0) {
      unsigned old = __hip_atomic_fetch_add(grp, 1u, __ATOMIC_ACQ_REL,
                                            __HIP_MEMORY_SCOPE_AGENT);
      if (old == 31u)
        __hip_atomic_fetch_add(root, 1u, __ATOMIC_RELEASE,
                               __HIP_MEMORY_SCOPE_AGENT);
    }
    return;
  }
  if (tid == 0) {
    unsigned old = __hip_atomic_fetch_add(grp, 1u, __ATOMIC_ACQ_REL,
                                          __HIP_MEMORY_SCOPE_AGENT);
    if (old == 31u)
      __hip_atomic_fetch_add(root, 1u, __ATOMIC_RELEASE,
                             __HIP_MEMORY_SCOPE_AGENT);
    while (__hip_atomic_load(root, __ATOMIC_RELAXED,
                             __HIP_MEMORY_SCOPE_AGENT) < 64u) {
      __builtin_amdgcn_s_sleep(2);
    }
    (void)__hip_atomic_load(root, __ATOMIC_ACQUIRE, __HIP_MEMORY_SCOPE_AGENT);
  }
  __syncthreads();

  // ---------------- phases C-F: 4 MLP layers, one feature/block ----------
  float* cT = ws + CT_OFF;
  float* hA = ws + H1_OFF;
  float* hB = ws + H2_OFF;
  const float* Wl[4] = {p.W0, p.W1, p.W2, p.W3};
  const float* Bl[4] = {p.B0, p.B1, p.B2, p.B3};
  const float* Gl[4] = {p.G0, p.G1, p.G2, p.G3};
  const float* El[4] = {p.E0, p.E1, p.E2, p.E3};
  const float* xs[4] = {cT, hA, hB, hA};
  float* ys[4] = {hA, hB, hA, nullptr};

  for (int l = 0; l < 4; ++l) {
    const int o = blk;
    const int bb = tid & 63;
    const int w = __builtin_amdgcn_readfirstlane(tid >> 6);  // scalar wave id
    const float* wr = Wl[l] + o * NH + w * 64;   // wave-uniform -> s_load
    const float* xp = xs[l] + (w * 64) * 64 + bb;
    float acc = 0.f;
#pragma unroll
    for (int i = 0; i < 64; ++i) acc += xp[i * 64] * wr[i];
    sm.l.part[w][bb] = acc;
    __syncthreads();
    if (w == 0) {
      float t = sm.l.part[0][bb] + sm.l.part[1][bb] + sm.l.part[2][bb] +
                sm.l.part[3][bb] + Bl[l][o];
      float s1 = t;
      for (int off = 32; off; off >>= 1) s1 += __shfl_xor(s1, off);
      float m = s1 * (1.f / 64.f);
      float d = t - m;
      float s2 = d * d;
      for (int off = 32; off; off >>= 1) s2 += __shfl_xor(s2, off);
      float var = s2 * (1.f / 64.f);
      float h = Gl[l][o] * d * rsqrtf(var + EPS_BN) + El[l][o];
      h = fmaxf(h, 0.f);
      if (l == 3) {
        atomicAdd(&p.out[bb], p.w4[o] * h);
      } else {
        ys[l][o * 64 + bb] = h;
      }
    }
    if (l < 3) grid_bar(grp, root, 47u + 16u * l, 80u + 16u * l);
  }
}

extern "C" void kernel_launch(void* const* d_in, const int* in_sizes, int n_in,
                              void* d_out, int out_size, void* d_ws,
                              size_t ws_size, hipStream_t stream) {
  Params p;
  p.xyz = (const float*)d_in[0];
  p.data = (const float*)d_in[1];
  p.l3 = (const float*)d_in[2];
  p.temp = (const float*)d_in[3];
  p.W0 = (const float*)d_in[4];  p.B0 = (const float*)d_in[5];
  p.G0 = (const float*)d_in[6];  p.E0 = (const float*)d_in[7];
  p.W1 = (const float*)d_in[8];  p.B1 = (const float*)d_in[9];
  p.G1 = (const float*)d_in[10]; p.E1 = (const float*)d_in[11];
  p.W2 = (const float*)d_in[12]; p.B2 = (const float*)d_in[13];
  p.G2 = (const float*)d_in[14]; p.E2 = (const float*)d_in[15];
  p.W3 = (const float*)d_in[16]; p.B3 = (const float*)d_in[17];
  p.G3 = (const float*)d_in[18]; p.E3 = (const float*)d_in[19];
  p.w4 = (const float*)d_in[20]; p.b4 = (const float*)d_in[21];
  p.out = (float*)d_out;
  p.ws = (float*)d_ws;

  // zero group counters + root (ws is poisoned 0xAA before every launch)
  hipMemsetAsync((char*)d_ws + (size_t)GRP_OFF * 4, 0, 1040 * 4, stream);
  mega<<<1024, 256, 0, stream>>>(p);
}